// Round 12
// baseline (132.685 us; speedup 1.0000x reference)
//
#include <hip/hip_runtime.h>
#include <float.h>
#include <math.h>

typedef __attribute__((ext_vector_type(8))) short short8;
typedef __attribute__((ext_vector_type(8))) _Float16 half8;
typedef __attribute__((ext_vector_type(4))) float f32x4;

constexpr int B_N  = 8192;
constexpr int D_K  = 128;
constexpr int K_AUG = 192;            // 128 real + 64 one-hot penalty dims
constexpr int NKQ  = 24;
constexpr int NCLS = 50;
constexpr int NCHUNK = 32;            // 256 cols per chunk -> grid 2048
constexpr int CCOLS = 256;
constexpr int NPBLK = 32;
constexpr float C_SCALE = 28.853900817779268f;  // 20*log2(e), folded into A
constexpr float PEN  = 4096.0f;                 // same-class penalty (base-2 units)
constexpr float SKIP = -34.0f;                  // tile-skip threshold vs global max
constexpr float NEG_LOW = -1.0e5f;

__device__ __forceinline__ float exp2fast(float x) { return __builtin_amdgcn_exp2f(x); }

// ---------------- prep: augmented A (scaled, -PEN one-hot) and k-major augmented B ----------------
__global__ void prep_kernel(const float* __restrict__ a, const float* __restrict__ b,
                            const int* __restrict__ labels,
                            short* __restrict__ aH, short* __restrict__ bT)
{
    const int NA = B_N * NKQ;
    int i = blockIdx.x * blockDim.x + threadIdx.x;
    if (i < NA) {
        int row = i / NKQ, kq = i - row * NKQ;
        short8 h;
        if (kq < 16) {
            const f32x4* sp = (const f32x4*)(a + (size_t)row * D_K + kq * 8);
            f32x4 v0 = sp[0], v1 = sp[1];
#pragma unroll
            for (int e = 0; e < 4; ++e) {
                h[e]     = __builtin_bit_cast(short, (_Float16)(C_SCALE * v0[e]));
                h[e + 4] = __builtin_bit_cast(short, (_Float16)(C_SCALE * v1[e]));
            }
        } else {
            int lab = labels[row];
            int base = (kq - 16) * 8;
#pragma unroll
            for (int e = 0; e < 8; ++e)
                h[e] = __builtin_bit_cast(short, (lab == base + e) ? (_Float16)(-PEN)
                                                                   : (_Float16)0.0f);
        }
        *(short8*)(aH + (size_t)row * K_AUG + kq * 8) = h;
    } else if (i < NA + B_N) {
        int col = i - NA;
        int lab = labels[col];
#pragma unroll 4
        for (int kq = 0; kq < 16; ++kq) {
            const f32x4* sp = (const f32x4*)(b + (size_t)col * D_K + kq * 8);
            f32x4 v0 = sp[0], v1 = sp[1];
            short8 h;
#pragma unroll
            for (int e = 0; e < 4; ++e) {
                h[e]     = __builtin_bit_cast(short, (_Float16)v0[e]);
                h[e + 4] = __builtin_bit_cast(short, (_Float16)v1[e]);
            }
            *(short8*)(bT + ((size_t)kq * B_N + col) * 8) = h;
        }
#pragma unroll
        for (int kq = 16; kq < 24; ++kq) {
            int base = (kq - 16) * 8;
            short8 h;
#pragma unroll
            for (int e = 0; e < 8; ++e)
                h[e] = __builtin_bit_cast(short, (lab == base + e) ? (_Float16)1.0f
                                                                   : (_Float16)0.0f);
            *(short8*)(bT + ((size_t)kq * B_N + col) * 8) = h;
        }
    }
}

// ---------------- pass 1: masked row max per chunk. Epilogue = 8 max3/tile, ZERO exp2 ----------------
__global__ __launch_bounds__(256)
void pass1_max(const short* __restrict__ aH, const short* __restrict__ bT,
               float* __restrict__ pmx)
{
    const int bid = blockIdx.x;
    const int chunk = bid & (NCHUNK - 1);
    const int R0 = (bid >> 5) * 128;
    const int C0 = chunk * CCOLS;
    const int tid = threadIdx.x;
    const int wid = tid >> 6, l = tid & 63;
    const int l15 = l & 15, l16 = l >> 4;
    const int wrow = R0 + wid * 32;

    half8 aF[2][6];
#pragma unroll
    for (int mf = 0; mf < 2; ++mf) {
        const int arow = wrow + mf * 16 + l15;
#pragma unroll
        for (int ks = 0; ks < 6; ++ks)
            aF[mf][ks] = __builtin_bit_cast(half8,
                *(const short8*)(aH + (size_t)arow * K_AUG + ks * 32 + l16 * 8));
    }

    float mx[8];
#pragma unroll
    for (int i = 0; i < 8; ++i) mx[i] = NEG_LOW;

    const char* cb = (const char*)bT + (size_t)C0 * 16;
    int vo[2][6];
#pragma unroll
    for (int nf = 0; nf < 2; ++nf)
#pragma unroll
        for (int ks = 0; ks < 6; ++ks)
            vo[nf][ks] = ((ks * 4 + l16) * B_N + nf * 16 + l15) * 16;

    half8 bF[2][6];
#pragma unroll
    for (int nf = 0; nf < 2; ++nf)
#pragma unroll
        for (int ks = 0; ks < 6; ++ks)
            bF[nf][ks] = __builtin_bit_cast(half8, *(const short8*)(cb + vo[nf][ks]));

    const f32x4 zz = f32x4{0.f, 0.f, 0.f, 0.f};
    for (int tt = 0; tt < 2; ++tt) {                 // 2 outer x 4 inner = 8 tiles
        const char* cbt = cb + tt * 2048;
#pragma unroll
        for (int ti = 0; ti < 4; ++ti) {
            f32x4 acc[2][2];
#pragma unroll
            for (int mf = 0; mf < 2; ++mf)
#pragma unroll
                for (int nf = 0; nf < 2; ++nf)
                    acc[mf][nf] = __builtin_amdgcn_mfma_f32_16x16x32_f16(
                        aF[mf][0], bF[nf][0], zz, 0, 0, 0);
#pragma unroll
            for (int ks = 1; ks < 6; ++ks)
#pragma unroll
                for (int mf = 0; mf < 2; ++mf)
#pragma unroll
                    for (int nf = 0; nf < 2; ++nf)
                        acc[mf][nf] = __builtin_amdgcn_mfma_f32_16x16x32_f16(
                            aF[mf][ks], bF[nf][ks], acc[mf][nf], 0, 0, 0);

            if (!(tt == 1 && ti == 3)) {
#pragma unroll
                for (int nf = 0; nf < 2; ++nf)
#pragma unroll
                    for (int ks = 0; ks < 6; ++ks)
                        bF[nf][ks] = __builtin_bit_cast(half8,
                            *(const short8*)(cbt + vo[nf][ks] + (ti + 1) * 512));
            }

#pragma unroll
            for (int mf = 0; mf < 2; ++mf)
#pragma unroll
                for (int r = 0; r < 4; ++r)
                    mx[mf * 4 + r] = fmaxf(fmaxf(mx[mf * 4 + r], acc[mf][0][r]),
                                           acc[mf][1][r]);     // -> v_max3
        }
    }

#pragma unroll
    for (int i = 0; i < 8; ++i) {
        float m = mx[i];
#pragma unroll
        for (int off = 1; off < 16; off <<= 1) m = fmaxf(m, __shfl_xor(m, off));
        if (l15 == 0) {
            int row = wrow + (i >> 2) * 16 + l16 * 4 + (i & 3);
            pmx[chunk * B_N + row] = m;
        }
    }
}

// ---------------- pass 2: global masked max per row ----------------
__global__ void combine_kernel(const float* __restrict__ pmx, float* __restrict__ mxF)
{
    int j = blockIdx.x * blockDim.x + threadIdx.x;
    float m = -FLT_MAX;
#pragma unroll 8
    for (int c = 0; c < NCHUNK; ++c) m = fmaxf(m, pmx[(size_t)c * B_N + j]);
    mxF[j] = m;
}

// ---------------- pass 3: s = sum 2^(d - mxF) per (chunk,row); tile-skip vote vs global ref ----------------
__global__ __launch_bounds__(256)
void pass3_sum(const short* __restrict__ aH, const short* __restrict__ bT,
               const float* __restrict__ mxF, float* __restrict__ ps)
{
    const int bid = blockIdx.x;
    const int chunk = bid & (NCHUNK - 1);
    const int R0 = (bid >> 5) * 128;
    const int C0 = chunk * CCOLS;
    const int tid = threadIdx.x;
    const int wid = tid >> 6, l = tid & 63;
    const int l15 = l & 15, l16 = l >> 4;
    const int wrow = R0 + wid * 32;

    half8 aF[2][6];
#pragma unroll
    for (int mf = 0; mf < 2; ++mf) {
        const int arow = wrow + mf * 16 + l15;
#pragma unroll
        for (int ks = 0; ks < 6; ++ks)
            aF[mf][ks] = __builtin_bit_cast(half8,
                *(const short8*)(aH + (size_t)arow * K_AUG + ks * 32 + l16 * 8));
    }

    f32x4 bias[2];                   // C-in = -global masked max per row
#pragma unroll
    for (int mf = 0; mf < 2; ++mf)
#pragma unroll
        for (int r = 0; r < 4; ++r)
            bias[mf][r] = -mxF[wrow + mf * 16 + l16 * 4 + r];

    float sm[8];
#pragma unroll
    for (int i = 0; i < 8; ++i) sm[i] = 0.0f;

    const char* cb = (const char*)bT + (size_t)C0 * 16;
    int vo[2][6];
#pragma unroll
    for (int nf = 0; nf < 2; ++nf)
#pragma unroll
        for (int ks = 0; ks < 6; ++ks)
            vo[nf][ks] = ((ks * 4 + l16) * B_N + nf * 16 + l15) * 16;

    half8 bF[2][6];
#pragma unroll
    for (int nf = 0; nf < 2; ++nf)
#pragma unroll
        for (int ks = 0; ks < 6; ++ks)
            bF[nf][ks] = __builtin_bit_cast(half8, *(const short8*)(cb + vo[nf][ks]));

    for (int tt = 0; tt < 2; ++tt) {
        const char* cbt = cb + tt * 2048;
#pragma unroll
        for (int ti = 0; ti < 4; ++ti) {
            f32x4 acc[2][2];
#pragma unroll
            for (int mf = 0; mf < 2; ++mf)
#pragma unroll
                for (int nf = 0; nf < 2; ++nf)
                    acc[mf][nf] = __builtin_amdgcn_mfma_f32_16x16x32_f16(
                        aF[mf][0], bF[nf][0], bias[mf], 0, 0, 0);
#pragma unroll
            for (int ks = 1; ks < 6; ++ks)
#pragma unroll
                for (int mf = 0; mf < 2; ++mf)
#pragma unroll
                    for (int nf = 0; nf < 2; ++nf)
                        acc[mf][nf] = __builtin_amdgcn_mfma_f32_16x16x32_f16(
                            aF[mf][ks], bF[nf][ks], acc[mf][nf], 0, 0, 0);

            if (!(tt == 1 && ti == 3)) {
#pragma unroll
                for (int nf = 0; nf < 2; ++nf)
#pragma unroll
                    for (int ks = 0; ks < 6; ++ks)
                        bF[nf][ks] = __builtin_bit_cast(half8,
                            *(const short8*)(cbt + vo[nf][ks] + (ti + 1) * 512));
            }

            // skip vote: all v <= 0; tile matters only if some cell > SKIP
            float t0 = fmaxf(fmaxf(acc[0][0][0], acc[0][0][1]), fmaxf(acc[0][0][2], acc[0][0][3]));
            float t1 = fmaxf(fmaxf(acc[0][1][0], acc[0][1][1]), fmaxf(acc[0][1][2], acc[0][1][3]));
            float t2 = fmaxf(fmaxf(acc[1][0][0], acc[1][0][1]), fmaxf(acc[1][0][2], acc[1][0][3]));
            float t3 = fmaxf(fmaxf(acc[1][1][0], acc[1][1][1]), fmaxf(acc[1][1][2], acc[1][1][3]));
            float tmax = fmaxf(fmaxf(t0, t1), fmaxf(t2, t3));
            if (__any(tmax > SKIP)) {
#pragma unroll
                for (int mf = 0; mf < 2; ++mf)
#pragma unroll
                    for (int r = 0; r < 4; ++r)
                        sm[mf * 4 + r] += exp2fast(acc[mf][0][r]) + exp2fast(acc[mf][1][r]);
            }
        }
    }

    // plain sum across the 16 column-lanes (common frame -> no exp2 in tail)
#pragma unroll
    for (int i = 0; i < 8; ++i) {
        float s = sm[i];
#pragma unroll
        for (int off = 1; off < 16; off <<= 1) s += __shfl_xor(s, off);
        if (l15 == 0) {
            int row = wrow + (i >> 2) * 16 + l16 * 4 + (i & 3);
            ps[chunk * B_N + row] = s;
        }
    }
}

// ---------------- classsum: plain chunk-sum + per-block class partials ----------------
__global__ void classsum_kernel(const float* __restrict__ ps, const int* __restrict__ labels,
                                float* __restrict__ partSum, unsigned int* __restrict__ partCnt)
{
    __shared__ float        csL[NCLS];
    __shared__ unsigned int ccL[NCLS];
    int t = threadIdx.x;
    if (t < NCLS) { csL[t] = 0.0f; ccL[t] = 0u; }
    __syncthreads();

    int j = blockIdx.x * blockDim.x + t;
    float s = 0.0f;
#pragma unroll 8
    for (int c = 0; c < NCHUNK; ++c) s += ps[(size_t)c * B_N + j];
    int lab = labels[j];
    atomicAdd(&csL[lab], s);
    atomicAdd(&ccL[lab], 1u);
    __syncthreads();
    if (t < NCLS) {
        partSum[blockIdx.x * NCLS + t] = csL[t];
        partCnt[blockIdx.x * NCLS + t] = ccL[t];
    }
}

__global__ void loss_kernel(const float* __restrict__ partSum,
                            const unsigned int* __restrict__ partCnt,
                            float* __restrict__ out)
{
    int c = threadIdx.x;
    float cs = 0.0f;
    unsigned int cc = 0u;
    if (c < NCLS) {
#pragma unroll 4
        for (int b = 0; b < NPBLK; ++b) {
            cs += partSum[b * NCLS + c];
            cc += partCnt[b * NCLS + c];
        }
    }

    float tot = cs;
#pragma unroll
    for (int off = 1; off < 64; off <<= 1) tot += __shfl_xor(tot, off);

    float contrib = 0.0f;
    if (c < NCLS && cc > 0u) {
        float negc = (float)(B_N - (int)cc);
        float nds  = tot - cs;
        float x    = (negc > 0.0f) ? (nds / negc) : nds;
        float lp   = (cc >= 2u) ? (-logf(x + 1e-12f)) : 0.0f;
        contrib = (float)cc * lp;
    }
#pragma unroll
    for (int off = 1; off < 64; off <<= 1) contrib += __shfl_xor(contrib, off);
    if (c == 0) out[0] = -(contrib / (float)B_N);
}

extern "C" void kernel_launch(void* const* d_in, const int* in_sizes, int n_in,
                              void* d_out, int out_size, void* d_ws, size_t ws_size,
                              hipStream_t stream)
{
    const float* anchor = (const float*)d_in[0];
    const float* target = (const float*)d_in[1];
    const int*   labels = (const int*)d_in[2];
    float* out = (float*)d_out;

    const size_t PLANE = (size_t)B_N * K_AUG * sizeof(short);   // 3 MB
    char* ws = (char*)d_ws;
    short* aH = (short*)(ws);
    short* bT = (short*)(ws + PLANE);
    float* pmx = (float*)(ws + 2 * PLANE);                       // 1 MB
    float* ps  = (float*)(ws + 2 * PLANE + (size_t)NCHUNK * B_N * 4);
    float* mxF = (float*)(ws + 2 * PLANE + 2 * (size_t)NCHUNK * B_N * 4);
    char*  cls = ws + 2 * PLANE + 2 * (size_t)NCHUNK * B_N * 4 + B_N * 4;
    float*        partSum = (float*)cls;
    unsigned int* partCnt = (unsigned int*)(cls + NPBLK * NCLS * sizeof(float));

    const int nprep = B_N * NKQ + B_N;
    prep_kernel<<<nprep / 256, 256, 0, stream>>>(anchor, target, labels, aH, bT);
    pass1_max<<<(B_N / 128) * NCHUNK, 256, 0, stream>>>(aH, bT, pmx);
    combine_kernel<<<B_N / 256, 256, 0, stream>>>(pmx, mxF);
    pass3_sum<<<(B_N / 128) * NCHUNK, 256, 0, stream>>>(aH, bT, mxF, ps);
    classsum_kernel<<<B_N / 256, 256, 0, stream>>>(ps, labels, partSum, partCnt);
    loss_kernel<<<1, 64, 0, stream>>>(partSum, partCnt, out);
}

// Round 13
// 64.515 us; speedup vs baseline: 2.0567x; 2.0567x over previous
//
#include <hip/hip_runtime.h>
#include <float.h>
#include <math.h>

typedef __attribute__((ext_vector_type(8))) short short8;
typedef __attribute__((ext_vector_type(8))) _Float16 half8;
typedef __attribute__((ext_vector_type(4))) float f32x4;

constexpr int B_N  = 8192;
constexpr int D_K  = 128;
constexpr int NCLS = 50;
constexpr int NCHK = 64;              // one chunk per 128-col block tile
constexpr int NPBLK = 32;
constexpr float C_SCALE  = 28.853900817779268f;   // 20*log2(e), folded into A
constexpr float NEG_LOW  = -1.0e5f;               // row-max floor (masks all-masked rows)
constexpr float NEG_MASK = -1.0e30f;              // masked-cell sentinel

__device__ __forceinline__ float exp2fast(float x) { return __builtin_amdgcn_exp2f(x); }
__device__ __forceinline__ f32x4 mfma16(half8 a, half8 b, f32x4 c) {
    return __builtin_amdgcn_mfma_f32_16x16x32_f16(a, b, c, 0, 0, 0);
}
__device__ __forceinline__ void async_copy16(void* lds, const void* g) {
    __builtin_amdgcn_global_load_lds((const __attribute__((address_space(1))) unsigned int*)g,
                                     (__attribute__((address_space(3))) unsigned int*)lds,
                                     16, 0, 0);
}

// ---------------- prep: f32 -> f16 row-major; A pre-scaled by C_SCALE ----------------
__global__ void prep_kernel(const float* __restrict__ a, const float* __restrict__ b,
                            short* __restrict__ aH, short* __restrict__ bH)
{
    const int NPER = B_N * D_K / 8;                  // 131072
    int i = blockIdx.x * blockDim.x + threadIdx.x;
    const float* src = (i < NPER) ? a : b;
    short*       dst = (i < NPER) ? aH : bH;
    const float  sc  = (i < NPER) ? C_SCALE : 1.0f;
    int j = (i < NPER) ? i : i - NPER;
    const f32x4* sp = (const f32x4*)(src + (size_t)j * 8);
    f32x4 v0 = sp[0], v1 = sp[1];
    short8 h;
#pragma unroll
    for (int e = 0; e < 4; ++e) {
        h[e]     = __builtin_bit_cast(short, (_Float16)(sc * v0[e]));
        h[e + 4] = __builtin_bit_cast(short, (_Float16)(sc * v1[e]));
    }
    *(short8*)(dst + (size_t)j * 8) = h;
}

// ---------------- main: 128x128 tile block-GEMM (K=128 single shot) + fused epilogue ----------------
// 4 waves (wr,wc in 2x2), each 64x64 via 4x4 MFMA frags. A,B tiles in LDS (64 KB),
// staged once via global_load_lds (pre-swizzled source, XOR-swizzled reads).
// Swapped mfma(b,a): lane's output row = l15 -> row reduce is lane-local + 2 shuffles.
__global__ __launch_bounds__(256)
void rowstats_kernel(const short* __restrict__ aH, const short* __restrict__ bH,
                     const int* __restrict__ labels,
                     float* __restrict__ pmx, float* __restrict__ ps)
{
    __shared__ __align__(16) char smem[65536];       // A tile 32KB | B tile 32KB

    const int bid    = blockIdx.x;
    const int colblk = bid & 63;                     // same colblk -> same XCD (64%8==0)
    const int R0     = (bid >> 6) * 128;
    const int C0     = colblk * 128;

    const int tid = threadIdx.x;
    const int wid = tid >> 6, l = tid & 63;
    const int l15 = l & 15, l16 = l >> 4;
    const int wr = wid >> 1, wc = wid & 1;

    // labels (issued first; latency hides under staging)
    int labA[4];
#pragma unroll
    for (int mf = 0; mf < 4; ++mf)
        labA[mf] = labels[R0 + wr * 64 + mf * 16 + l15];
    int lb[4][4];
#pragma unroll
    for (int nf = 0; nf < 4; ++nf) {
        int4 t4 = *(const int4*)(labels + C0 + wc * 64 + nf * 16 + l16 * 4);
        lb[nf][0] = t4.x; lb[nf][1] = t4.y; lb[nf][2] = t4.z; lb[nf][3] = t4.w;
    }

    // ---- stage A+B tiles: LDS[row][slot16B], slot holds global granule slot^(row&7) ----
    {
        const int srow = tid >> 4;                   // 0..15 within each 16-row issue
        const int sp   = tid & 15;
#pragma unroll
        for (int is = 0; is < 8; ++is) {
            int row = is * 16 + srow;
            int gs  = sp ^ (row & 7);
            char* da = smem + is * 4096 + (wid << 10);     // wave-uniform base (+lane*16 by HW)
            async_copy16(da,         aH + (size_t)(R0 + row) * D_K + gs * 8);
            async_copy16(da + 32768, bH + (size_t)(C0 + row) * D_K + gs * 8);
        }
    }
    __syncthreads();                                 // vmcnt drained by barrier

    // ---- K=128 MFMA sweep: 4 k-steps x 4x4 frags, operands SWAPPED ----
    f32x4 acc[4][4];
#pragma unroll
    for (int mf = 0; mf < 4; ++mf)
#pragma unroll
        for (int nf = 0; nf < 4; ++nf) acc[mf][nf] = f32x4{0.f, 0.f, 0.f, 0.f};

    const int swz = l15 & 7;
#pragma unroll
    for (int ks = 0; ks < 4; ++ks) {
        const int g = (ks * 4 + l16) ^ swz;
        half8 af[4], bf[4];
#pragma unroll
        for (int mf = 0; mf < 4; ++mf) {
            int row = wr * 64 + mf * 16 + l15;
            af[mf] = *(const half8*)(smem + row * 256 + g * 16);
        }
#pragma unroll
        for (int nf = 0; nf < 4; ++nf) {
            int row = wc * 64 + nf * 16 + l15;
            bf[nf] = *(const half8*)(smem + 32768 + row * 256 + g * 16);
        }
#pragma unroll
        for (int mf = 0; mf < 4; ++mf)
#pragma unroll
            for (int nf = 0; nf < 4; ++nf)
                acc[mf][nf] = mfma16(bf[nf], af[mf], acc[mf][nf]);   // D[col][row]: row = l15
    }

    // ---- epilogue: per row-slot mf (row = wr*64+mf*16+l15): 16 lane-local cells ----
    float fm[4], fs[4];
#pragma unroll
    for (int mf = 0; mf < 4; ++mf) {
        const int la = labA[mf];
        float v[16];
        float m = NEG_LOW;
#pragma unroll
        for (int nf = 0; nf < 4; ++nf)
#pragma unroll
            for (int r = 0; r < 4; ++r) {
                float x = (lb[nf][r] != la) ? acc[mf][nf][r] : NEG_MASK;
                v[nf * 4 + r] = x;
                m = fmaxf(m, x);
            }
        float s0 = 0.f, s1 = 0.f, s2 = 0.f, s3 = 0.f;
#pragma unroll
        for (int k = 0; k < 4; ++k) {
            s0 += exp2fast(v[k]      - m);
            s1 += exp2fast(v[k + 4]  - m);
            s2 += exp2fast(v[k + 8]  - m);
            s3 += exp2fast(v[k + 12] - m);
        }
        float s = (s0 + s1) + (s2 + s3);
        // combine across the 4 l16 groups (lanes l, l^16, l^32, l^48 share l15)
#pragma unroll
        for (int off = 16; off < 64; off <<= 1) {
            float m2 = __shfl_xor(m, off);
            float sx = __shfl_xor(s, off);
            float nm = fmaxf(m, m2);
            s = s * exp2fast(m - nm) + sx * exp2fast(m2 - nm);
            m = nm;
        }
        fm[mf] = m; fs[mf] = s;
    }

    // ---- cross-wc merge via smem reuse (all tile reads done) ----
    __syncthreads();
    float* mb = (float*)smem;                        // [128 rows][2]
    if (wc == 1 && l < 16) {
#pragma unroll
        for (int mf = 0; mf < 4; ++mf) {
            int rl = wr * 64 + mf * 16 + l15;
            mb[rl * 2]     = fm[mf];
            mb[rl * 2 + 1] = fs[mf];
        }
    }
    __syncthreads();
    if (wc == 0 && l < 16) {
#pragma unroll
        for (int mf = 0; mf < 4; ++mf) {
            int rl = wr * 64 + mf * 16 + l15;
            float m2 = mb[rl * 2], s2 = mb[rl * 2 + 1];
            float nm = fmaxf(fm[mf], m2);
            float s  = fs[mf] * exp2fast(fm[mf] - nm) + s2 * exp2fast(m2 - nm);
            pmx[(size_t)colblk * B_N + R0 + rl] = nm;
            ps [(size_t)colblk * B_N + R0 + rl] = s;
        }
    }
}

// ---------------- classsum: two-phase 64-chunk combine + per-block class partials ----------------
__global__ void classsum_kernel(const float* __restrict__ pmx, const float* __restrict__ ps,
                                const int* __restrict__ labels,
                                float* __restrict__ partSum, unsigned int* __restrict__ partCnt)
{
    __shared__ float        csL[NCLS];
    __shared__ unsigned int ccL[NCLS];
    int t = threadIdx.x;
    if (t < NCLS) { csL[t] = 0.0f; ccL[t] = 0u; }
    __syncthreads();

    int j = blockIdx.x * blockDim.x + t;
    float m = -FLT_MAX;
#pragma unroll 8
    for (int c = 0; c < NCHK; ++c) m = fmaxf(m, pmx[(size_t)c * B_N + j]);
    float s = 0.0f;
#pragma unroll 8
    for (int c = 0; c < NCHK; ++c)
        s += ps[(size_t)c * B_N + j] * exp2fast(pmx[(size_t)c * B_N + j] - m);

    int lab = labels[j];
    atomicAdd(&csL[lab], s);
    atomicAdd(&ccL[lab], 1u);
    __syncthreads();
    if (t < NCLS) {
        partSum[blockIdx.x * NCLS + t] = csL[t];
        partCnt[blockIdx.x * NCLS + t] = ccL[t];
    }
}

__global__ void loss_kernel(const float* __restrict__ partSum,
                            const unsigned int* __restrict__ partCnt,
                            float* __restrict__ out)
{
    int c = threadIdx.x;  // 64 threads = 1 wave
    float cs = 0.0f;
    unsigned int cc = 0u;
    if (c < NCLS) {
#pragma unroll 4
        for (int b = 0; b < NPBLK; ++b) {
            cs += partSum[b * NCLS + c];
            cc += partCnt[b * NCLS + c];
        }
    }

    float tot = cs;
#pragma unroll
    for (int off = 1; off < 64; off <<= 1) tot += __shfl_xor(tot, off);

    float contrib = 0.0f;
    if (c < NCLS && cc > 0u) {
        float negc = (float)(B_N - (int)cc);
        float nds  = tot - cs;
        float x    = (negc > 0.0f) ? (nds / negc) : nds;
        float lp   = (cc >= 2u) ? (-logf(x + 1e-12f)) : 0.0f;
        contrib = (float)cc * lp;
    }
#pragma unroll
    for (int off = 1; off < 64; off <<= 1) contrib += __shfl_xor(contrib, off);
    if (c == 0) out[0] = -(contrib / (float)B_N);
}

extern "C" void kernel_launch(void* const* d_in, const int* in_sizes, int n_in,
                              void* d_out, int out_size, void* d_ws, size_t ws_size,
                              hipStream_t stream)
{
    const float* anchor = (const float*)d_in[0];
    const float* target = (const float*)d_in[1];
    const int*   labels = (const int*)d_in[2];
    float* out = (float*)d_out;

    const size_t PLANE = (size_t)B_N * D_K * sizeof(short);    // 2 MB
    const size_t PART  = (size_t)NCHK * B_N * sizeof(float);   // 2 MB
    char* ws = (char*)d_ws;
    short* aH = (short*)(ws);
    short* bH = (short*)(ws + PLANE);
    float* pmx = (float*)(ws + 2 * PLANE);
    float* ps  = (float*)(ws + 2 * PLANE + PART);
    char*  cls = ws + 2 * PLANE + 2 * PART;
    float*        partSum = (float*)cls;
    unsigned int* partCnt = (unsigned int*)(cls + NPBLK * NCLS * sizeof(float));

    prep_kernel<<<2 * (B_N * D_K / 8) / 256, 256, 0, stream>>>(anchor, target, aH, bH);
    rowstats_kernel<<<64 * 64, 256, 0, stream>>>(aH, bH, labels, pmx, ps);
    classsum_kernel<<<B_N / 256, 256, 0, stream>>>(pmx, ps, labels, partSum, partCnt);
    loss_kernel<<<1, 64, 0, stream>>>(partSum, partCnt, out);
}